// Round 4
// baseline (6547.957 us; speedup 1.0000x reference)
//
#include <hip/hip_runtime.h>
#include <math.h>

#define NB   512      // batch
#define SEQ  57
#define NP   56
#define CHN  256
#define DIM  512
#define MLPD 2048

typedef float f32x4 __attribute__((ext_vector_type(4)));
typedef short s16x8 __attribute__((ext_vector_type(8)));

__device__ __forceinline__ short f2bf(float f) {
    union { float f; unsigned u; } v; v.f = f;
    unsigned r = (v.u + 0x7fffu + ((v.u >> 16) & 1u)) >> 16;
    return (short)r;
}
__device__ __forceinline__ float geluf(float v) {
    return 0.5f * v * (1.0f + erff(v * 0.70710678118654752f));
}

// ---------------- compile-time ring tables (exact replica of outer_sampling) ----
struct RingTables { int tgt[224]; int s1[224]; int s2[224]; int start[8]; };
constexpr RingTables make_rings() {
    RingTables rt{};
    int n = 0; const int E = 15, mid = 7;
    rt.start[0] = 0;
    for (int i = 1; i <= 7; ++i) {
        int a1 = mid - i, a2 = mid + i, b1 = mid - i, b2 = mid + i;
        int d0 = 0, d1 = 1, l1 = a1, l2 = b1 - 1, started = 0;
        while (true) {
            l1 += d0; l2 += d1;
            if (l1 == a1 && l2 == b1) { if (started) break; started = 1; }
            if (l1 > a2)      { d0 = 0;  d1 = -1; l1 -= 1; continue; }
            else if (l2 < b1) { d0 = -1; d1 = 0;  l2 += 1; continue; }
            else if (l2 > b2) { d0 = 1;  d1 = 0;  l2 -= 1; continue; }
            if (l1 < 0 || l1 > E || l2 < 0 || l2 > E) continue;
            int m1 = -((l1 > mid) - (l1 < mid));
            int m2 = -((l2 > mid) - (l2 < mid));
            int ab1 = l1 > mid ? l1 - mid : mid - l1;
            int ab2 = l2 > mid ? l2 - mid : mid - l2;
            if (ab1 > ab2)      { rt.s1[n] = (l1+m1)*E + l2;   rt.s2[n] = (l1+m1)*E + l2+m2; }
            else if (ab1 < ab2) { rt.s1[n] = l1*E + l2+m2;     rt.s2[n] = (l1+m1)*E + l2+m2; }
            else                { int s = (l1+m1)*E + l2+m2;   rt.s1[n] = s; rt.s2[n] = s; }
            rt.tgt[n] = l1*E + l2;
            ++n;
        }
        rt.start[i] = n;
    }
    return rt;
}
constexpr RingTables RT_HOST = make_rings();
__constant__ RingTables RT = RT_HOST;

// ---------------- spiral preprocess: x[B,CH,225] -> tok bf16 [B,56,CH] ----------
__global__ __launch_bounds__(256) void spiral_kernel(const float* __restrict__ x,
                                                     short* __restrict__ tok) {
    __shared__ float tile[64 * 225];
    const int b  = blockIdx.x >> 2;
    const int c0 = (blockIdx.x & 3) << 6;
    const float* src = x + ((size_t)b * CHN + c0) * 225;
    for (int i = threadIdx.x; i < 64 * 225; i += 256) tile[i] = src[i];
    __syncthreads();
    for (int r = 0; r < 7; ++r) {
        const int s0 = RT.start[r], n = RT.start[r + 1] - s0;
        for (int w = threadIdx.x; w < (n << 6); w += 256) {
            const int c = w & 63, t = s0 + (w >> 6);
            float* row = tile + c * 225;
            row[RT.tgt[t]] += (row[RT.s1[t]] + row[RT.s2[t]]) * 0.25f;  // RATIO/2
        }
        __syncthreads();
    }
    for (int w = threadIdx.x; w < (56 << 6); w += 256) {
        const int c = w & 63, p = w >> 6;
        tok[((size_t)b * NP + p) * CHN + c0 + c] = f2bf(tile[c * 225 + RT.tgt[168 + p]]);
    }
}

// ---------------- weight transpose + fp32->bf16:  in[K][N] -> out[N][K] --------
__global__ __launch_bounds__(256) void transcvt(const float* __restrict__ in,
                                                short* __restrict__ out, int K, int N) {
    __shared__ float t[32][33];
    in  += (size_t)blockIdx.z * K * N;
    out += (size_t)blockIdx.z * K * N;
    const int k0 = blockIdx.y << 5, n0 = blockIdx.x << 5;
    const int tx = threadIdx.x & 31, ty = threadIdx.x >> 5;
    for (int i = ty; i < 32; i += 8) t[i][tx] = in[(size_t)(k0 + i) * N + n0 + tx];
    __syncthreads();
    for (int i = ty; i < 32; i += 8) out[(size_t)(n0 + i) * K + k0 + tx] = f2bf(t[tx][i]);
}

// ---------------- sinusoid positional table [57,512], fp64 math like numpy -----
__global__ __launch_bounds__(256) void pos_kernel(float* __restrict__ pos) {
    const int idx = blockIdx.x * 256 + threadIdx.x;
    const int t = idx >> 9, j = idx & 511;
    double expo = (double)(2 * (j >> 1)) / 512.0;
    double ang  = (double)t * pow(10000.0, -expo);
    pos[idx] = (j & 1) ? (float)cos(ang) : (float)sin(ang);
}

// ---------------- h[B,57,512] = concat(cls, emb) + POS -------------------------
__global__ __launch_bounds__(256) void assemble_kernel(const float* __restrict__ emb,
                                                       const float* __restrict__ cls,
                                                       const float* __restrict__ pos,
                                                       float* __restrict__ h) {
    const unsigned idx = blockIdx.x * 256 + threadIdx.x;
    const int c = idx & 511;
    const int r = (idx >> 9) % SEQ;
    const unsigned b = idx / (SEQ * DIM);
    float base = (r == 0) ? cls[c] : emb[((size_t)b * NP + (r - 1)) * DIM + c];
    h[idx] = base + pos[r * DIM + c];
}

// ---------------- LayerNorm (fp32 in, bf16 out), one wave per row --------------
__global__ __launch_bounds__(256) void ln_kernel(const float* __restrict__ x,
                                                 const float* __restrict__ g,
                                                 const float* __restrict__ bta,
                                                 short* __restrict__ y) {
    const int row  = (blockIdx.x << 2) + (threadIdx.x >> 6);
    const int lane = threadIdx.x & 63;
    const float* xr = x + (size_t)row * DIM;
    float v[8]; float s = 0.f;
#pragma unroll
    for (int j = 0; j < 8; ++j) { v[j] = xr[lane + (j << 6)]; s += v[j]; }
#pragma unroll
    for (int off = 1; off < 64; off <<= 1) s += __shfl_xor(s, off);
    const float mu = s * (1.f / 512.f);
    float sq = 0.f;
#pragma unroll
    for (int j = 0; j < 8; ++j) { const float d = v[j] - mu; sq += d * d; }
#pragma unroll
    for (int off = 1; off < 64; off <<= 1) sq += __shfl_xor(sq, off);
    const float rs = rsqrtf(sq * (1.f / 512.f) + 1e-5f);
    short* yr = y + (size_t)row * DIM;
#pragma unroll
    for (int j = 0; j < 8; ++j) {
        const int c = lane + (j << 6);
        yr[c] = f2bf((v[j] - mu) * rs * g[c] + bta[c]);
    }
}

// ---------------- bf16 MFMA GEMM, flatmm-style (no LDS, no barriers) -----------
// C[M,N] = A[M,K] @ BT[N,K]^T (+bias,+gelu,+res). 128x128 block, 4 waves,
// each wave = 64x64 via 4x4 MFMA 16x16x32 subtiles. Fragments loaded directly
// from global (verified A-layout: m=lane&15, k=8*(lane>>4)+j; 16-row x 64B
// footprint per load). Register ping-pong prefetch; K-loop is barrier-free.
template<int ACT, bool RES, bool OUTBF>
__global__ __launch_bounds__(256, 3) void gemm_bf16(
    const short* __restrict__ A, const short* __restrict__ BT,
    const float* __restrict__ bias, const float* __restrict__ res,
    void* __restrict__ Cout, int M, int N, int K)
{
    const int tid  = threadIdx.x;
    const int m0 = blockIdx.y << 7, n0 = blockIdx.x << 7;
    const int wave = tid >> 6, lane = tid & 63;
    const int wm = (wave >> 1) << 6, wn = (wave & 1) << 6;
    const int fm = lane & 15, fq = lane >> 4;

    const short* Ap[4]; const short* Bp[4];
#pragma unroll
    for (int s = 0; s < 4; ++s) {
        Ap[s] = A  + (size_t)(m0 + wm + s * 16 + fm) * K + (fq << 3);
        Bp[s] = BT + (size_t)(n0 + wn + s * 16 + fm) * K + (fq << 3);
    }

    f32x4 acc[4][4] = {};
    s16x8 a0[4], b0[4], a1[4], b1[4];
#pragma unroll
    for (int s = 0; s < 4; ++s) { a0[s] = *(const s16x8*)(Ap[s]); b0[s] = *(const s16x8*)(Bp[s]); }

    for (int k0 = 0; k0 < K; k0 += 64) {
        const int kn1 = k0 + 32;                       // K % 64 == 0 -> always valid
        const int kn2 = (k0 + 64 < K) ? k0 + 64 : 0;   // harmless in-bounds dummy on last iter
#pragma unroll
        for (int s = 0; s < 4; ++s) { a1[s] = *(const s16x8*)(Ap[s] + kn1); b1[s] = *(const s16x8*)(Bp[s] + kn1); }
#pragma unroll
        for (int i = 0; i < 4; ++i)
#pragma unroll
            for (int j = 0; j < 4; ++j)
                acc[i][j] = __builtin_amdgcn_mfma_f32_16x16x32_bf16(a0[i], b0[j], acc[i][j], 0, 0, 0);
#pragma unroll
        for (int s = 0; s < 4; ++s) { a0[s] = *(const s16x8*)(Ap[s] + kn2); b0[s] = *(const s16x8*)(Bp[s] + kn2); }
#pragma unroll
        for (int i = 0; i < 4; ++i)
#pragma unroll
            for (int j = 0; j < 4; ++j)
                acc[i][j] = __builtin_amdgcn_mfma_f32_16x16x32_bf16(a1[i], b1[j], acc[i][j], 0, 0, 0);
    }

#pragma unroll
    for (int i = 0; i < 4; ++i) {
#pragma unroll
        for (int r = 0; r < 4; ++r) {
            const int row = m0 + wm + i * 16 + (fq << 2) + r;
#pragma unroll
            for (int j = 0; j < 4; ++j) {
                const int col = n0 + wn + j * 16 + fm;
                float v = acc[i][j][r];
                if (bias) v += bias[col];
                if (ACT == 1) v = geluf(v);
                if (RES) v += res[(size_t)row * N + col];
                if (OUTBF) ((short*)Cout)[(size_t)row * N + col] = f2bf(v);
                else       ((float*)Cout)[(size_t)row * N + col] = v;
            }
        }
    }
}

// ---------------- MFMA attention: one wave per (b, head) -----------------------
// qkv is bf16 [B*57][1536] (q|k|v, head-major 64). o is bf16 [B*57][512].
__global__ __launch_bounds__(64) void attn_mfma(const short* __restrict__ qkv,
                                                short* __restrict__ o) {
    __shared__ short Pl[64 * 72];
    __shared__ short Vt[64 * 72];
    const int b = blockIdx.x >> 3, hd = blockIdx.x & 7;
    const int lane = threadIdx.x;
    const int n = lane & 15, q = lane >> 4;
    const short* base = qkv + (size_t)b * SEQ * 1536 + hd * 64;

    // stage V transposed: Vt[d][t] = V[t][d]; zero pad rows t>=57
    {
        const short* vb = base + 1024 + lane;
        for (int t = 0; t < SEQ; ++t) Vt[lane * 72 + t] = vb[(size_t)t * 1536];
        for (int t = SEQ; t < 64; ++t) Vt[lane * 72 + t] = 0;
    }

    // Q,K fragments directly from global (A layout: m=lane&15, k=q*8+j)
    const s16x8 zero8 = {};
    s16x8 qf[4][2], kf[4][2];
#pragma unroll
    for (int ti = 0; ti < 4; ++ti) {
        const int tq = ti * 16 + n;
#pragma unroll
        for (int kk = 0; kk < 2; ++kk) {
            const int ko = kk * 32 + q * 8;
            qf[ti][kk] = (tq < SEQ) ? *(const s16x8*)(base + (size_t)tq * 1536 + ko)       : zero8;
            kf[ti][kk] = (tq < SEQ) ? *(const s16x8*)(base + 512 + (size_t)tq * 1536 + ko) : zero8;
        }
    }

    f32x4 sacc[4][4] = {};
#pragma unroll
    for (int ti = 0; ti < 4; ++ti)
#pragma unroll
        for (int tj = 0; tj < 4; ++tj)
#pragma unroll
            for (int kk = 0; kk < 2; ++kk)
                sacc[ti][tj] = __builtin_amdgcn_mfma_f32_16x16x32_bf16(
                    qf[ti][kk], kf[tj][kk], sacc[ti][tj], 0, 0, 0);

    // softmax per row (row = ti*16 + q*4 + r, cols across tj & 16 lanes)
#pragma unroll
    for (int ti = 0; ti < 4; ++ti) {
#pragma unroll
        for (int r = 0; r < 4; ++r) {
            float v[4]; float mx = -1e30f;
#pragma unroll
            for (int tj = 0; tj < 4; ++tj) {
                float s = sacc[ti][tj][r] * 0.125f;       // SCALE = 64^-0.5
                if (tj * 16 + n >= SEQ) s = -1e30f;       // mask pad cols
                v[tj] = s; mx = fmaxf(mx, s);
            }
            mx = fmaxf(mx, __shfl_xor(mx, 1));
            mx = fmaxf(mx, __shfl_xor(mx, 2));
            mx = fmaxf(mx, __shfl_xor(mx, 4));
            mx = fmaxf(mx, __shfl_xor(mx, 8));
            float sum = 0.f;
#pragma unroll
            for (int tj = 0; tj < 4; ++tj) { v[tj] = __expf(v[tj] - mx); sum += v[tj]; }
            sum += __shfl_xor(sum, 1); sum += __shfl_xor(sum, 2);
            sum += __shfl_xor(sum, 4); sum += __shfl_xor(sum, 8);
            const float inv = 1.f / sum;
            const int row = ti * 16 + q * 4 + r;
#pragma unroll
            for (int tj = 0; tj < 4; ++tj)
                Pl[row * 72 + tj * 16 + n] = f2bf(v[tj] * inv);
        }
    }
    __syncthreads();

    // O = P @ V  (A from Pl, B from Vt; both 2-way-free b128 reads)
    f32x4 oacc[4][4] = {};
#pragma unroll
    for (int kk = 0; kk < 2; ++kk) {
        s16x8 pf[4], vf[4];
#pragma unroll
        for (int s = 0; s < 4; ++s) {
            pf[s] = *(const s16x8*)(Pl + (s * 16 + n) * 72 + kk * 32 + q * 8);
            vf[s] = *(const s16x8*)(Vt + (s * 16 + n) * 72 + kk * 32 + q * 8);
        }
#pragma unroll
        for (int ti = 0; ti < 4; ++ti)
#pragma unroll
            for (int td = 0; td < 4; ++td)
                oacc[ti][td] = __builtin_amdgcn_mfma_f32_16x16x32_bf16(
                    pf[ti], vf[td], oacc[ti][td], 0, 0, 0);
    }
#pragma unroll
    for (int ti = 0; ti < 4; ++ti) {
#pragma unroll
        for (int r = 0; r < 4; ++r) {
            const int trow = ti * 16 + q * 4 + r;
            if (trow < SEQ) {
#pragma unroll
                for (int td = 0; td < 4; ++td)
                    o[((size_t)(b * SEQ + trow)) * DIM + hd * 64 + td * 16 + n]
                        = f2bf(oacc[ti][td][r]);
            }
        }
    }
}

// ---------------- head: mean-pool + LN + [512x16] matvec -----------------------
__global__ __launch_bounds__(256) void head_kernel(const float* __restrict__ h,
                                                   const float* __restrict__ g,
                                                   const float* __restrict__ bb,
                                                   const float* __restrict__ Wh,
                                                   const float* __restrict__ bh,
                                                   float* __restrict__ out) {
    __shared__ float p[DIM];
    __shared__ float r1[4], r2[4];
    const int b = blockIdx.x;
    const float* hb = h + (size_t)b * SEQ * DIM;
    for (int c = threadIdx.x; c < DIM; c += 256) {
        float s = 0.f;
        for (int t = 0; t < SEQ; ++t) s += hb[t * DIM + c];
        p[c] = s * (1.f / 57.f);
    }
    __syncthreads();
    float s = 0.f;
    for (int c = threadIdx.x; c < DIM; c += 256) s += p[c];
#pragma unroll
    for (int off = 1; off < 64; off <<= 1) s += __shfl_xor(s, off);
    if ((threadIdx.x & 63) == 0) r1[threadIdx.x >> 6] = s;
    __syncthreads();
    const float mu = (r1[0] + r1[1] + r1[2] + r1[3]) * (1.f / 512.f);
    float sq = 0.f;
    for (int c = threadIdx.x; c < DIM; c += 256) { float d = p[c] - mu; sq += d * d; }
#pragma unroll
    for (int off = 1; off < 64; off <<= 1) sq += __shfl_xor(sq, off);
    if ((threadIdx.x & 63) == 0) r2[threadIdx.x >> 6] = sq;
    __syncthreads();
    const float rs = rsqrtf((r2[0] + r2[1] + r2[2] + r2[3]) * (1.f / 512.f) + 1e-5f);
    for (int c = threadIdx.x; c < DIM; c += 256) p[c] = (p[c] - mu) * rs * g[c] + bb[c];
    __syncthreads();
    if (threadIdx.x < 16) {
        float acc = bh[threadIdx.x];
        for (int c = 0; c < DIM; ++c) acc += p[c] * Wh[c * 16 + threadIdx.x];
        out[b * 16 + threadIdx.x] = acc;
    }
}

// ---------------- orchestration -------------------------------------------------
extern "C" void kernel_launch(void* const* d_in, const int* in_sizes, int n_in,
                              void* d_out, int out_size, void* d_ws, size_t ws_size,
                              hipStream_t stream) {
    (void)in_sizes; (void)n_in; (void)out_size; (void)ws_size;
    const float* x    = (const float*)d_in[0];
    const float* We   = (const float*)d_in[1];
    const float* be   = (const float*)d_in[2];
    const float* cls  = (const float*)d_in[3];
    const float* Wqkv = (const float*)d_in[4];
    const float* Wo   = (const float*)d_in[5];
    const float* bo   = (const float*)d_in[6];
    const float* ln1g = (const float*)d_in[7];
    const float* ln1b = (const float*)d_in[8];
    const float* W1   = (const float*)d_in[9];
    const float* b1   = (const float*)d_in[10];
    const float* W2   = (const float*)d_in[11];
    const float* b2   = (const float*)d_in[12];
    const float* ln2g = (const float*)d_in[13];
    const float* ln2b = (const float*)d_in[14];
    const float* lnhg = (const float*)d_in[15];
    const float* lnhb = (const float*)d_in[16];
    const float* Wh   = (const float*)d_in[17];
    const float* bh   = (const float*)d_in[18];

    char* ws = (char*)d_ws;
    float* h    = (float*)(ws);                      // 512*57*512*4  = 59,768,832
    float* big  = (float*)(ws + 59768832);           // 512*57*1536*4 = 179,306,496 (fp32 embed)
    short* bigs = (short*)big;                       // aliased bf16 view (qkv / MLP hidden)
    short* ybf  = (short*)(ws + 239075328);          // 512*57*512*2  = 29,884,416
    short* wbuf = (short*)(ws + 268959744);          // 38,010,880
    short* tokb = (short*)(ws + 306970624);          // 512*56*256*2  = 14,680,064
    float* pos  = (float*)(ws + 321650688);          // 57*512*4      = 116,736

    short* WeT   = wbuf;                             // [512][256]
    short* WqkvT = wbuf + 131072;                    // 6 x [1536][512]
    short* WoT   = WqkvT + 6 * 786432;               // 6 x [512][512]
    short* W1T   = WoT   + 6 * 262144;               // 6 x [2048][512]
    short* W2T   = W1T   + 6 * 1048576;              // 6 x [512][2048]

    pos_kernel<<<114, 256, 0, stream>>>(pos);
    transcvt<<<dim3(16,  8, 1), 256, 0, stream>>>(We,   WeT,    256,  512);
    transcvt<<<dim3(48, 16, 6), 256, 0, stream>>>(Wqkv, WqkvT,  512, 1536);
    transcvt<<<dim3(16, 16, 6), 256, 0, stream>>>(Wo,   WoT,    512,  512);
    transcvt<<<dim3(64, 16, 6), 256, 0, stream>>>(W1,   W1T,    512, 2048);
    transcvt<<<dim3(16, 64, 6), 256, 0, stream>>>(W2,   W2T,   2048,  512);
    spiral_kernel<<<2048, 256, 0, stream>>>(x, tokb);

    gemm_bf16<0, false, false><<<dim3(4, 224), 256, 0, stream>>>(
        tokb, WeT, be, nullptr, big, NB * NP, DIM, CHN);
    assemble_kernel<<<(NB * SEQ * DIM) / 256, 256, 0, stream>>>(big, cls, pos, h);

    const int M = NB * SEQ;   // 29184
    for (int l = 0; l < 6; ++l) {
        ln_kernel<<<M / 4, 256, 0, stream>>>(h, ln1g + l * 512, ln1b + l * 512, ybf);
        gemm_bf16<0, false, true><<<dim3(12, 228), 256, 0, stream>>>(
            ybf, WqkvT + (size_t)l * 786432, nullptr, nullptr, bigs, M, 1536, 512);
        attn_mfma<<<NB * 8, 64, 0, stream>>>(bigs, ybf);
        gemm_bf16<0, true, false><<<dim3(4, 228), 256, 0, stream>>>(
            ybf, WoT + (size_t)l * 262144, bo + l * 512, h, h, M, 512, 512);
        ln_kernel<<<M / 4, 256, 0, stream>>>(h, ln2g + l * 512, ln2b + l * 512, ybf);
        gemm_bf16<1, false, true><<<dim3(16, 228), 256, 0, stream>>>(
            ybf, W1T + (size_t)l * 1048576, b1 + l * 2048, nullptr, bigs, M, 2048, 512);
        gemm_bf16<0, true, false><<<dim3(4, 228), 256, 0, stream>>>(
            bigs, W2T + (size_t)l * 1048576, b2 + l * 512, h, h, M, 512, 2048);
    }
    head_kernel<<<NB, 256, 0, stream>>>(h, lnhg, lnhb, Wh, bh, (float*)d_out);
}

// Round 5
// 2755.038 us; speedup vs baseline: 2.3767x; 2.3767x over previous
//
#include <hip/hip_runtime.h>
#include <math.h>

#define NB   512      // batch
#define SEQ  57
#define NP   56
#define CHN  256
#define DIM  512
#define MLPD 2048

typedef float f32x4 __attribute__((ext_vector_type(4)));
typedef short s16x8 __attribute__((ext_vector_type(8)));

__device__ __forceinline__ short f2bf(float f) {
    union { float f; unsigned u; } v; v.f = f;
    unsigned r = (v.u + 0x7fffu + ((v.u >> 16) & 1u)) >> 16;
    return (short)r;
}
__device__ __forceinline__ float geluf(float v) {
    return 0.5f * v * (1.0f + erff(v * 0.70710678118654752f));
}

#define GLDS16(g, l) __builtin_amdgcn_global_load_lds(                         \
    (const __attribute__((address_space(1))) void*)(g),                        \
    (__attribute__((address_space(3))) void*)(l), 16, 0, 0)

// ---------------- compile-time ring tables (exact replica of outer_sampling) ----
struct RingTables { int tgt[224]; int s1[224]; int s2[224]; int start[8]; };
constexpr RingTables make_rings() {
    RingTables rt{};
    int n = 0; const int E = 15, mid = 7;
    rt.start[0] = 0;
    for (int i = 1; i <= 7; ++i) {
        int a1 = mid - i, a2 = mid + i, b1 = mid - i, b2 = mid + i;
        int d0 = 0, d1 = 1, l1 = a1, l2 = b1 - 1, started = 0;
        while (true) {
            l1 += d0; l2 += d1;
            if (l1 == a1 && l2 == b1) { if (started) break; started = 1; }
            if (l1 > a2)      { d0 = 0;  d1 = -1; l1 -= 1; continue; }
            else if (l2 < b1) { d0 = -1; d1 = 0;  l2 += 1; continue; }
            else if (l2 > b2) { d0 = 1;  d1 = 0;  l2 -= 1; continue; }
            if (l1 < 0 || l1 > E || l2 < 0 || l2 > E) continue;
            int m1 = -((l1 > mid) - (l1 < mid));
            int m2 = -((l2 > mid) - (l2 < mid));
            int ab1 = l1 > mid ? l1 - mid : mid - l1;
            int ab2 = l2 > mid ? l2 - mid : mid - l2;
            if (ab1 > ab2)      { rt.s1[n] = (l1+m1)*E + l2;   rt.s2[n] = (l1+m1)*E + l2+m2; }
            else if (ab1 < ab2) { rt.s1[n] = l1*E + l2+m2;     rt.s2[n] = (l1+m1)*E + l2+m2; }
            else                { int s = (l1+m1)*E + l2+m2;   rt.s1[n] = s; rt.s2[n] = s; }
            rt.tgt[n] = l1*E + l2;
            ++n;
        }
        rt.start[i] = n;
    }
    return rt;
}
constexpr RingTables RT_HOST = make_rings();
__constant__ RingTables RT = RT_HOST;

// ---------------- spiral preprocess: x[B,CH,225] -> tok bf16 [B,56,CH] ----------
__global__ __launch_bounds__(256) void spiral_kernel(const float* __restrict__ x,
                                                     short* __restrict__ tok) {
    __shared__ float tile[64 * 225];
    const int b  = blockIdx.x >> 2;
    const int c0 = (blockIdx.x & 3) << 6;
    const float* src = x + ((size_t)b * CHN + c0) * 225;
    for (int i = threadIdx.x; i < 64 * 225; i += 256) tile[i] = src[i];
    __syncthreads();
    for (int r = 0; r < 7; ++r) {
        const int s0 = RT.start[r], n = RT.start[r + 1] - s0;
        for (int w = threadIdx.x; w < (n << 6); w += 256) {
            const int c = w & 63, t = s0 + (w >> 6);
            float* row = tile + c * 225;
            row[RT.tgt[t]] += (row[RT.s1[t]] + row[RT.s2[t]]) * 0.25f;  // RATIO/2
        }
        __syncthreads();
    }
    for (int w = threadIdx.x; w < (56 << 6); w += 256) {
        const int c = w & 63, p = w >> 6;
        tok[((size_t)b * NP + p) * CHN + c0 + c] = f2bf(tile[c * 225 + RT.tgt[168 + p]]);
    }
}

// ---------------- weight transpose + fp32->bf16:  in[K][N] -> out[N][K] --------
__global__ __launch_bounds__(256) void transcvt(const float* __restrict__ in,
                                                short* __restrict__ out, int K, int N) {
    __shared__ float t[32][33];
    in  += (size_t)blockIdx.z * K * N;
    out += (size_t)blockIdx.z * K * N;
    const int k0 = blockIdx.y << 5, n0 = blockIdx.x << 5;
    const int tx = threadIdx.x & 31, ty = threadIdx.x >> 5;
    for (int i = ty; i < 32; i += 8) t[i][tx] = in[(size_t)(k0 + i) * N + n0 + tx];
    __syncthreads();
    for (int i = ty; i < 32; i += 8) out[(size_t)(n0 + i) * K + k0 + tx] = f2bf(t[tx][i]);
}

// ---------------- sinusoid positional table [57,512], fp64 math like numpy -----
__global__ __launch_bounds__(256) void pos_kernel(float* __restrict__ pos) {
    const int idx = blockIdx.x * 256 + threadIdx.x;
    const int t = idx >> 9, j = idx & 511;
    double expo = (double)(2 * (j >> 1)) / 512.0;
    double ang  = (double)t * pow(10000.0, -expo);
    pos[idx] = (j & 1) ? (float)cos(ang) : (float)sin(ang);
}

// ---------------- h[B,57,512] = concat(cls, emb) + POS -------------------------
__global__ __launch_bounds__(256) void assemble_kernel(const float* __restrict__ emb,
                                                       const float* __restrict__ cls,
                                                       const float* __restrict__ pos,
                                                       float* __restrict__ h) {
    const unsigned idx = blockIdx.x * 256 + threadIdx.x;
    const int c = idx & 511;
    const int r = (idx >> 9) % SEQ;
    const unsigned b = idx / (SEQ * DIM);
    float base = (r == 0) ? cls[c] : emb[((size_t)b * NP + (r - 1)) * DIM + c];
    h[idx] = base + pos[r * DIM + c];
}

// ---------------- LayerNorm (fp32 in, bf16 out), one wave per row --------------
__global__ __launch_bounds__(256) void ln_kernel(const float* __restrict__ x,
                                                 const float* __restrict__ g,
                                                 const float* __restrict__ bta,
                                                 short* __restrict__ y) {
    const int row  = (blockIdx.x << 2) + (threadIdx.x >> 6);
    const int lane = threadIdx.x & 63;
    const float* xr = x + (size_t)row * DIM;
    float v[8]; float s = 0.f;
#pragma unroll
    for (int j = 0; j < 8; ++j) { v[j] = xr[lane + (j << 6)]; s += v[j]; }
#pragma unroll
    for (int off = 1; off < 64; off <<= 1) s += __shfl_xor(s, off);
    const float mu = s * (1.f / 512.f);
    float sq = 0.f;
#pragma unroll
    for (int j = 0; j < 8; ++j) { const float d = v[j] - mu; sq += d * d; }
#pragma unroll
    for (int off = 1; off < 64; off <<= 1) sq += __shfl_xor(sq, off);
    const float rs = rsqrtf(sq * (1.f / 512.f) + 1e-5f);
    short* yr = y + (size_t)row * DIM;
#pragma unroll
    for (int j = 0; j < 8; ++j) {
        const int c = lane + (j << 6);
        yr[c] = f2bf((v[j] - mu) * rs * g[c] + bta[c]);
    }
}

// ---------------- bf16 MFMA GEMM: C[M,N] = A[M,K] @ BT[N,K]^T (+bias,+act,+res)
// 256x128 tile, 512 threads (8 waves, each 64x64), BK=64, global_load_lds
// width-16 staging with XOR chunk swizzle (verified 0 bank conflicts in R3).
// LDS 48 KB -> 3 blocks/CU -> 24 waves/CU.
template<int ACT, bool RES, bool OUTBF>
__global__ __launch_bounds__(512, 4) void gemm_bf16(
    const short* __restrict__ A, const short* __restrict__ BT,
    const float* __restrict__ bias, const float* __restrict__ res,
    void* __restrict__ Cout, int M, int N, int K)
{
    __shared__ short As[256 * 64];    // 32 KB
    __shared__ short Bs[128 * 64];    // 16 KB
    const int tid = threadIdx.x;
    const int m0 = blockIdx.y << 8, n0 = blockIdx.x << 7;
    const int wave = tid >> 6, lane = tid & 63;
    const int wm = (wave >> 1) << 6;      // 0,64,128,192
    const int wn = (wave & 1) << 6;       // 0,64
    const int fm = lane & 15, fq = lane >> 4;

    // A: 2048 16B chunks (4/thread); B: 1024 chunks (2/thread).
    // LDS slot g holds global chunk (row=g>>3, c=(g&7)^(row&7)).
    const short* Ap[4]; short* lA[4];
    const short* Bp[2]; short* lB[2];
#pragma unroll
    for (int t = 0; t < 4; ++t) {
        const int g = t * 512 + tid;
        const int row = g >> 3, c = (g & 7) ^ (row & 7);
        Ap[t] = A + (size_t)(m0 + row) * K + (c << 3);
        lA[t] = As + g * 8;
    }
#pragma unroll
    for (int t = 0; t < 2; ++t) {
        const int g = t * 512 + tid;
        const int row = g >> 3, c = (g & 7) ^ (row & 7);
        Bp[t] = BT + (size_t)(n0 + row) * K + (c << 3);
        lB[t] = Bs + g * 8;
    }

    f32x4 acc[4][4] = {};

    for (int k0 = 0; k0 < K; k0 += 64) {
        __syncthreads();
#pragma unroll
        for (int t = 0; t < 4; ++t) GLDS16(Ap[t] + k0, lA[t]);
#pragma unroll
        for (int t = 0; t < 2; ++t) GLDS16(Bp[t] + k0, lB[t]);
        __syncthreads();
#pragma unroll
        for (int kk = 0; kk < 2; ++kk) {
            const int cs = ((fq + (kk << 2)) ^ (fm & 7)) << 3;
            s16x8 af[4], bfr[4];
#pragma unroll
            for (int s = 0; s < 4; ++s) {
                af[s]  = *(const s16x8*)(As + (wm + s * 16 + fm) * 64 + cs);
                bfr[s] = *(const s16x8*)(Bs + (wn + s * 16 + fm) * 64 + cs);
            }
#pragma unroll
            for (int i = 0; i < 4; ++i)
#pragma unroll
                for (int j = 0; j < 4; ++j)
                    acc[i][j] = __builtin_amdgcn_mfma_f32_16x16x32_bf16(af[i], bfr[j], acc[i][j], 0, 0, 0);
        }
    }

#pragma unroll
    for (int i = 0; i < 4; ++i) {
#pragma unroll
        for (int r = 0; r < 4; ++r) {
            const int row = m0 + wm + i * 16 + (fq << 2) + r;
#pragma unroll
            for (int j = 0; j < 4; ++j) {
                const int col = n0 + wn + j * 16 + fm;
                float v = acc[i][j][r];
                if (bias) v += bias[col];
                if (ACT == 1) v = geluf(v);
                if (RES) v += res[(size_t)row * N + col];
                if (OUTBF) ((short*)Cout)[(size_t)row * N + col] = f2bf(v);
                else       ((float*)Cout)[(size_t)row * N + col] = v;
            }
        }
    }
}

// ---------------- MFMA attention: one wave per (b, head) -----------------------
// qkv is bf16 [B*57][1536] (q|k|v, head-major 64). o is bf16 [B*57][512].
__global__ __launch_bounds__(64) void attn_mfma(const short* __restrict__ qkv,
                                                short* __restrict__ o) {
    __shared__ short Pl[64 * 72];
    __shared__ short Vt[64 * 72];
    const int b = blockIdx.x >> 3, hd = blockIdx.x & 7;
    const int lane = threadIdx.x;
    const int n = lane & 15, q = lane >> 4;
    const short* base = qkv + (size_t)b * SEQ * 1536 + hd * 64;

    // stage V transposed: Vt[d][t] = V[t][d]; zero pad rows t>=57
    {
        const short* vb = base + 1024 + lane;
        for (int t = 0; t < SEQ; ++t) Vt[lane * 72 + t] = vb[(size_t)t * 1536];
        for (int t = SEQ; t < 64; ++t) Vt[lane * 72 + t] = 0;
    }

    // Q,K fragments directly from global (A layout: m=lane&15, k=q*8+j)
    const s16x8 zero8 = {};
    s16x8 qf[4][2], kf[4][2];
#pragma unroll
    for (int ti = 0; ti < 4; ++ti) {
        const int tq = ti * 16 + n;
#pragma unroll
        for (int kk = 0; kk < 2; ++kk) {
            const int ko = kk * 32 + q * 8;
            qf[ti][kk] = (tq < SEQ) ? *(const s16x8*)(base + (size_t)tq * 1536 + ko)       : zero8;
            kf[ti][kk] = (tq < SEQ) ? *(const s16x8*)(base + 512 + (size_t)tq * 1536 + ko) : zero8;
        }
    }

    f32x4 sacc[4][4] = {};
#pragma unroll
    for (int ti = 0; ti < 4; ++ti)
#pragma unroll
        for (int tj = 0; tj < 4; ++tj)
#pragma unroll
            for (int kk = 0; kk < 2; ++kk)
                sacc[ti][tj] = __builtin_amdgcn_mfma_f32_16x16x32_bf16(
                    qf[ti][kk], kf[tj][kk], sacc[ti][tj], 0, 0, 0);

    // softmax per row (row = ti*16 + q*4 + r, cols across tj & 16 lanes)
#pragma unroll
    for (int ti = 0; ti < 4; ++ti) {
#pragma unroll
        for (int r = 0; r < 4; ++r) {
            float v[4]; float mx = -1e30f;
#pragma unroll
            for (int tj = 0; tj < 4; ++tj) {
                float s = sacc[ti][tj][r] * 0.125f;       // SCALE = 64^-0.5
                if (tj * 16 + n >= SEQ) s = -1e30f;       // mask pad cols
                v[tj] = s; mx = fmaxf(mx, s);
            }
            mx = fmaxf(mx, __shfl_xor(mx, 1));
            mx = fmaxf(mx, __shfl_xor(mx, 2));
            mx = fmaxf(mx, __shfl_xor(mx, 4));
            mx = fmaxf(mx, __shfl_xor(mx, 8));
            float sum = 0.f;
#pragma unroll
            for (int tj = 0; tj < 4; ++tj) { v[tj] = __expf(v[tj] - mx); sum += v[tj]; }
            sum += __shfl_xor(sum, 1); sum += __shfl_xor(sum, 2);
            sum += __shfl_xor(sum, 4); sum += __shfl_xor(sum, 8);
            const float inv = 1.f / sum;
            const int row = ti * 16 + q * 4 + r;
#pragma unroll
            for (int tj = 0; tj < 4; ++tj)
                Pl[row * 72 + tj * 16 + n] = f2bf(v[tj] * inv);
        }
    }
    __syncthreads();

    // O = P @ V  (A from Pl, B from Vt; both 2-way-free b128 reads)
    f32x4 oacc[4][4] = {};
#pragma unroll
    for (int kk = 0; kk < 2; ++kk) {
        s16x8 pf[4], vf[4];
#pragma unroll
        for (int s = 0; s < 4; ++s) {
            pf[s] = *(const s16x8*)(Pl + (s * 16 + n) * 72 + kk * 32 + q * 8);
            vf[s] = *(const s16x8*)(Vt + (s * 16 + n) * 72 + kk * 32 + q * 8);
        }
#pragma unroll
        for (int ti = 0; ti < 4; ++ti)
#pragma unroll
            for (int td = 0; td < 4; ++td)
                oacc[ti][td] = __builtin_amdgcn_mfma_f32_16x16x32_bf16(
                    pf[ti], vf[td], oacc[ti][td], 0, 0, 0);
    }
#pragma unroll
    for (int ti = 0; ti < 4; ++ti) {
#pragma unroll
        for (int r = 0; r < 4; ++r) {
            const int trow = ti * 16 + q * 4 + r;
            if (trow < SEQ) {
#pragma unroll
                for (int td = 0; td < 4; ++td)
                    o[((size_t)(b * SEQ + trow)) * DIM + hd * 64 + td * 16 + n]
                        = f2bf(oacc[ti][td][r]);
            }
        }
    }
}

// ---------------- head: mean-pool + LN + [512x16] matvec -----------------------
__global__ __launch_bounds__(256) void head_kernel(const float* __restrict__ h,
                                                   const float* __restrict__ g,
                                                   const float* __restrict__ bb,
                                                   const float* __restrict__ Wh,
                                                   const float* __restrict__ bh,
                                                   float* __restrict__ out) {
    __shared__ float p[DIM];
    __shared__ float r1[4], r2[4];
    const int b = blockIdx.x;
    const float* hb = h + (size_t)b * SEQ * DIM;
    for (int c = threadIdx.x; c < DIM; c += 256) {
        float s = 0.f;
        for (int t = 0; t < SEQ; ++t) s += hb[t * DIM + c];
        p[c] = s * (1.f / 57.f);
    }
    __syncthreads();
    float s = 0.f;
    for (int c = threadIdx.x; c < DIM; c += 256) s += p[c];
#pragma unroll
    for (int off = 1; off < 64; off <<= 1) s += __shfl_xor(s, off);
    if ((threadIdx.x & 63) == 0) r1[threadIdx.x >> 6] = s;
    __syncthreads();
    const float mu = (r1[0] + r1[1] + r1[2] + r1[3]) * (1.f / 512.f);
    float sq = 0.f;
    for (int c = threadIdx.x; c < DIM; c += 256) { float d = p[c] - mu; sq += d * d; }
#pragma unroll
    for (int off = 1; off < 64; off <<= 1) sq += __shfl_xor(sq, off);
    if ((threadIdx.x & 63) == 0) r2[threadIdx.x >> 6] = sq;
    __syncthreads();
    const float rs = rsqrtf((r2[0] + r2[1] + r2[2] + r2[3]) * (1.f / 512.f) + 1e-5f);
    for (int c = threadIdx.x; c < DIM; c += 256) p[c] = (p[c] - mu) * rs * g[c] + bb[c];
    __syncthreads();
    if (threadIdx.x < 16) {
        float acc = bh[threadIdx.x];
        for (int c = 0; c < DIM; ++c) acc += p[c] * Wh[c * 16 + threadIdx.x];
        out[b * 16 + threadIdx.x] = acc;
    }
}

// ---------------- orchestration -------------------------------------------------
extern "C" void kernel_launch(void* const* d_in, const int* in_sizes, int n_in,
                              void* d_out, int out_size, void* d_ws, size_t ws_size,
                              hipStream_t stream) {
    (void)in_sizes; (void)n_in; (void)out_size; (void)ws_size;
    const float* x    = (const float*)d_in[0];
    const float* We   = (const float*)d_in[1];
    const float* be   = (const float*)d_in[2];
    const float* cls  = (const float*)d_in[3];
    const float* Wqkv = (const float*)d_in[4];
    const float* Wo   = (const float*)d_in[5];
    const float* bo   = (const float*)d_in[6];
    const float* ln1g = (const float*)d_in[7];
    const float* ln1b = (const float*)d_in[8];
    const float* W1   = (const float*)d_in[9];
    const float* b1   = (const float*)d_in[10];
    const float* W2   = (const float*)d_in[11];
    const float* b2   = (const float*)d_in[12];
    const float* ln2g = (const float*)d_in[13];
    const float* ln2b = (const float*)d_in[14];
    const float* lnhg = (const float*)d_in[15];
    const float* lnhb = (const float*)d_in[16];
    const float* Wh   = (const float*)d_in[17];
    const float* bh   = (const float*)d_in[18];

    char* ws = (char*)d_ws;
    float* h    = (float*)(ws);                      // 512*57*512*4  = 59,768,832
    float* big  = (float*)(ws + 59768832);           // 512*57*1536*4 = 179,306,496 (fp32 embed)
    short* bigs = (short*)big;                       // aliased bf16 view (qkv / MLP hidden)
    short* ybf  = (short*)(ws + 239075328);          // 512*57*512*2  = 29,884,416
    short* wbuf = (short*)(ws + 268959744);          // 38,010,880
    short* tokb = (short*)(ws + 306970624);          // 512*56*256*2  = 14,680,064
    float* pos  = (float*)(ws + 321650688);          // 57*512*4      = 116,736

    short* WeT   = wbuf;                             // [512][256]
    short* WqkvT = wbuf + 131072;                    // 6 x [1536][512]
    short* WoT   = WqkvT + 6 * 786432;               // 6 x [512][512]
    short* W1T   = WoT   + 6 * 262144;               // 6 x [2048][512]
    short* W2T   = W1T   + 6 * 1048576;              // 6 x [512][2048]

    pos_kernel<<<114, 256, 0, stream>>>(pos);
    transcvt<<<dim3(16,  8, 1), 256, 0, stream>>>(We,   WeT,    256,  512);
    transcvt<<<dim3(48, 16, 6), 256, 0, stream>>>(Wqkv, WqkvT,  512, 1536);
    transcvt<<<dim3(16, 16, 6), 256, 0, stream>>>(Wo,   WoT,    512,  512);
    transcvt<<<dim3(64, 16, 6), 256, 0, stream>>>(W1,   W1T,    512, 2048);
    transcvt<<<dim3(16, 64, 6), 256, 0, stream>>>(W2,   W2T,   2048,  512);
    spiral_kernel<<<2048, 256, 0, stream>>>(x, tokb);

    // patch embedding: emb[B*56,512] = tok @ We + be  (M = 28672 = 112*256)
    gemm_bf16<0, false, false><<<dim3(4, 112), 512, 0, stream>>>(
        tokb, WeT, be, nullptr, big, NB * NP, DIM, CHN);
    assemble_kernel<<<(NB * SEQ * DIM) / 256, 256, 0, stream>>>(big, cls, pos, h);

    const int M = NB * SEQ;   // 29184 = 114*256
    for (int l = 0; l < 6; ++l) {
        ln_kernel<<<M / 4, 256, 0, stream>>>(h, ln1g + l * 512, ln1b + l * 512, ybf);
        gemm_bf16<0, false, true><<<dim3(12, 114), 512, 0, stream>>>(
            ybf, WqkvT + (size_t)l * 786432, nullptr, nullptr, bigs, M, 1536, 512);
        attn_mfma<<<NB * 8, 64, 0, stream>>>(bigs, ybf);
        gemm_bf16<0, true, false><<<dim3(4, 114), 512, 0, stream>>>(
            ybf, WoT + (size_t)l * 262144, bo + l * 512, h, h, M, 512, 512);
        ln_kernel<<<M / 4, 256, 0, stream>>>(h, ln2g + l * 512, ln2b + l * 512, ybf);
        gemm_bf16<1, false, true><<<dim3(16, 114), 512, 0, stream>>>(
            ybf, W1T + (size_t)l * 1048576, b1 + l * 2048, nullptr, bigs, M, 2048, 512);
        gemm_bf16<0, true, false><<<dim3(4, 114), 512, 0, stream>>>(
            bigs, W2T + (size_t)l * 1048576, b2 + l * 512, h, h, M, 512, 2048);
    }
    head_kernel<<<NB, 256, 0, stream>>>(h, lnhg, lnhb, Wh, bh, (float*)d_out);
}

// Round 6
// 2525.803 us; speedup vs baseline: 2.5924x; 1.0908x over previous
//
#include <hip/hip_runtime.h>
#include <math.h>

#define NB   512      // batch
#define SEQ  57
#define NP   56
#define CHN  256
#define DIM  512
#define MLPD 2048

typedef float f32x4 __attribute__((ext_vector_type(4)));
typedef short s16x8 __attribute__((ext_vector_type(8)));
typedef short s16x4 __attribute__((ext_vector_type(4)));

__device__ __forceinline__ short f2bf(float f) {
    union { float f; unsigned u; } v; v.f = f;
    unsigned r = (v.u + 0x7fffu + ((v.u >> 16) & 1u)) >> 16;
    return (short)r;
}
__device__ __forceinline__ float geluf(float v) {
    return 0.5f * v * (1.0f + erff(v * 0.70710678118654752f));
}

#define GLDS16(g, l) __builtin_amdgcn_global_load_lds(                         \
    (const __attribute__((address_space(1))) void*)(g),                        \
    (__attribute__((address_space(3))) void*)(l), 16, 0, 0)

// ---------------- compile-time ring tables (exact replica of outer_sampling) ----
struct RingTables { int tgt[224]; int s1[224]; int s2[224]; int start[8]; };
constexpr RingTables make_rings() {
    RingTables rt{};
    int n = 0; const int E = 15, mid = 7;
    rt.start[0] = 0;
    for (int i = 1; i <= 7; ++i) {
        int a1 = mid - i, a2 = mid + i, b1 = mid - i, b2 = mid + i;
        int d0 = 0, d1 = 1, l1 = a1, l2 = b1 - 1, started = 0;
        while (true) {
            l1 += d0; l2 += d1;
            if (l1 == a1 && l2 == b1) { if (started) break; started = 1; }
            if (l1 > a2)      { d0 = 0;  d1 = -1; l1 -= 1; continue; }
            else if (l2 < b1) { d0 = -1; d1 = 0;  l2 += 1; continue; }
            else if (l2 > b2) { d0 = 1;  d1 = 0;  l2 -= 1; continue; }
            if (l1 < 0 || l1 > E || l2 < 0 || l2 > E) continue;
            int m1 = -((l1 > mid) - (l1 < mid));
            int m2 = -((l2 > mid) - (l2 < mid));
            int ab1 = l1 > mid ? l1 - mid : mid - l1;
            int ab2 = l2 > mid ? l2 - mid : mid - l2;
            if (ab1 > ab2)      { rt.s1[n] = (l1+m1)*E + l2;   rt.s2[n] = (l1+m1)*E + l2+m2; }
            else if (ab1 < ab2) { rt.s1[n] = l1*E + l2+m2;     rt.s2[n] = (l1+m1)*E + l2+m2; }
            else                { int s = (l1+m1)*E + l2+m2;   rt.s1[n] = s; rt.s2[n] = s; }
            rt.tgt[n] = l1*E + l2;
            ++n;
        }
        rt.start[i] = n;
    }
    return rt;
}
constexpr RingTables RT_HOST = make_rings();
__constant__ RingTables RT = RT_HOST;

// ---------------- spiral preprocess: x[B,CH,225] -> tok bf16 [B,56,CH] ----------
__global__ __launch_bounds__(256) void spiral_kernel(const float* __restrict__ x,
                                                     short* __restrict__ tok) {
    __shared__ float tile[64 * 225];
    const int b  = blockIdx.x >> 2;
    const int c0 = (blockIdx.x & 3) << 6;
    const float* src = x + ((size_t)b * CHN + c0) * 225;
    for (int i = threadIdx.x; i < 64 * 225; i += 256) tile[i] = src[i];
    __syncthreads();
    for (int r = 0; r < 7; ++r) {
        const int s0 = RT.start[r], n = RT.start[r + 1] - s0;
        for (int w = threadIdx.x; w < (n << 6); w += 256) {
            const int c = w & 63, t = s0 + (w >> 6);
            float* row = tile + c * 225;
            row[RT.tgt[t]] += (row[RT.s1[t]] + row[RT.s2[t]]) * 0.25f;  // RATIO/2
        }
        __syncthreads();
    }
    for (int w = threadIdx.x; w < (56 << 6); w += 256) {
        const int c = w & 63, p = w >> 6;
        tok[((size_t)b * NP + p) * CHN + c0 + c] = f2bf(tile[c * 225 + RT.tgt[168 + p]]);
    }
}

// ---------------- weight transpose + fp32->bf16:  in[K][N] -> out[N][K] --------
__global__ __launch_bounds__(256) void transcvt(const float* __restrict__ in,
                                                short* __restrict__ out, int K, int N) {
    __shared__ float t[32][33];
    in  += (size_t)blockIdx.z * K * N;
    out += (size_t)blockIdx.z * K * N;
    const int k0 = blockIdx.y << 5, n0 = blockIdx.x << 5;
    const int tx = threadIdx.x & 31, ty = threadIdx.x >> 5;
    for (int i = ty; i < 32; i += 8) t[i][tx] = in[(size_t)(k0 + i) * N + n0 + tx];
    __syncthreads();
    for (int i = ty; i < 32; i += 8) out[(size_t)(n0 + i) * K + k0 + tx] = f2bf(t[tx][i]);
}

// ---------------- sinusoid positional table [57,512], fp64 math like numpy -----
__global__ __launch_bounds__(256) void pos_kernel(float* __restrict__ pos) {
    const int idx = blockIdx.x * 256 + threadIdx.x;
    const int t = idx >> 9, j = idx & 511;
    double expo = (double)(2 * (j >> 1)) / 512.0;
    double ang  = (double)t * pow(10000.0, -expo);
    pos[idx] = (j & 1) ? (float)cos(ang) : (float)sin(ang);
}

// ---------------- h row 0 per batch: cls + pos[0] ------------------------------
__global__ __launch_bounds__(256) void cls_pos_kernel(const float* __restrict__ cls,
                                                      const float* __restrict__ pos,
                                                      float* __restrict__ h) {
    const int idx = blockIdx.x * 256 + threadIdx.x;   // grid exactly 512*512
    const int c = idx & 511, b = idx >> 9;
    h[(size_t)b * SEQ * DIM + c] = cls[c] + pos[c];
}

// ---------------- LayerNorm (fp32 in, bf16 out), one wave per row, float4 ------
__global__ __launch_bounds__(256) void ln_kernel(const float* __restrict__ x,
                                                 const float* __restrict__ g,
                                                 const float* __restrict__ bta,
                                                 short* __restrict__ y) {
    const int row  = (blockIdx.x << 2) + (threadIdx.x >> 6);
    const int lane = threadIdx.x & 63;
    const float* xr = x + (size_t)row * DIM;
    f32x4 v0 = *(const f32x4*)(xr + (lane << 2));
    f32x4 v1 = *(const f32x4*)(xr + (lane << 2) + 256);
    float s = v0[0] + v0[1] + v0[2] + v0[3] + v1[0] + v1[1] + v1[2] + v1[3];
#pragma unroll
    for (int off = 1; off < 64; off <<= 1) s += __shfl_xor(s, off);
    const float mu = s * (1.f / 512.f);
    float sq = 0.f;
#pragma unroll
    for (int k = 0; k < 4; ++k) { float d = v0[k] - mu; sq += d * d; }
#pragma unroll
    for (int k = 0; k < 4; ++k) { float d = v1[k] - mu; sq += d * d; }
#pragma unroll
    for (int off = 1; off < 64; off <<= 1) sq += __shfl_xor(sq, off);
    const float rs = rsqrtf(sq * (1.f / 512.f) + 1e-5f);
    short* yr = y + (size_t)row * DIM;
#pragma unroll
    for (int p = 0; p < 2; ++p) {
        const int c0 = (lane << 2) + (p << 8);
        const f32x4 vv = p ? v1 : v0;
        const f32x4 g4 = *(const f32x4*)(g + c0);
        const f32x4 b4 = *(const f32x4*)(bta + c0);
        s16x4 o;
#pragma unroll
        for (int k = 0; k < 4; ++k) o[k] = f2bf((vv[k] - mu) * rs * g4[k] + b4[k]);
        *(s16x4*)(yr + c0) = o;
    }
}

// ---------------- bf16 MFMA GEMM: C[M,N] = A[M,K] @ BT[N,K]^T ------------------
// 128x128 tile, BK=64, global_load_lds width-16 with XOR chunk swizzle
// (0 bank conflicts, verified R3). MFMA operands SWAPPED (bfr first) so each
// lane's 4 acc regs span 4 consecutive COLUMNS -> float4/short4 epilogue.
// EMB variant scatters rows to h[b*57+t+1] adding POS (passed via `res`).
template<int ACT, bool RES, bool OUTBF, bool EMB>
__global__ __launch_bounds__(256, 2) void gemm_bf16(
    const short* __restrict__ A, const short* __restrict__ BT,
    const float* __restrict__ bias, const float* __restrict__ res,
    void* __restrict__ Cout, int M, int N, int K)
{
    __shared__ short As[128 * 64];
    __shared__ short Bs[128 * 64];
    const int tid = threadIdx.x;
    const int m0 = blockIdx.y << 7, n0 = blockIdx.x << 7;
    const int wave = tid >> 6, lane = tid & 63;
    const int wm = (wave >> 1) << 6, wn = (wave & 1) << 6;
    const int fm = lane & 15, fq = lane >> 4;

    const short* Ap[4]; const short* Bp[4];
    short *lA[4], *lB[4];
#pragma unroll
    for (int t = 0; t < 4; ++t) {
        const int g = t * 256 + tid;
        const int row = g >> 3;
        const int c = (g & 7) ^ (row & 7);
        Ap[t] = A  + (size_t)(m0 + row) * K + (c << 3);
        Bp[t] = BT + (size_t)(n0 + row) * K + (c << 3);
        lA[t] = As + g * 8;
        lB[t] = Bs + g * 8;
    }

    f32x4 acc[4][4] = {};

    for (int k0 = 0; k0 < K; k0 += 64) {
        __syncthreads();
#pragma unroll
        for (int t = 0; t < 4; ++t) GLDS16(Ap[t] + k0, lA[t]);
#pragma unroll
        for (int t = 0; t < 4; ++t) GLDS16(Bp[t] + k0, lB[t]);
        __syncthreads();
#pragma unroll
        for (int kk = 0; kk < 2; ++kk) {
            const int cs = ((fq + (kk << 2)) ^ (fm & 7)) << 3;
            s16x8 af[4], bfr[4];
#pragma unroll
            for (int s = 0; s < 4; ++s) {
                af[s]  = *(const s16x8*)(As + (wm + s * 16 + fm) * 64 + cs);
                bfr[s] = *(const s16x8*)(Bs + (wn + s * 16 + fm) * 64 + cs);
            }
#pragma unroll
            for (int i = 0; i < 4; ++i)
#pragma unroll
                for (int j = 0; j < 4; ++j)
                    acc[i][j] = __builtin_amdgcn_mfma_f32_16x16x32_bf16(bfr[j], af[i], acc[i][j], 0, 0, 0);
        }
    }

    // epilogue: lane holds rows (wm+i*16+fm), cols (wn+j*16+4*fq .. +3)
#pragma unroll
    for (int i = 0; i < 4; ++i) {
        const int row = m0 + wm + i * 16 + fm;
        size_t obase;
        const float* posr = nullptr;
        if (EMB) {
            const int bb = row / 56, tt = row - bb * 56;
            obase = ((size_t)(bb * SEQ + tt + 1)) * N;
            posr = res + (size_t)(tt + 1) * N;
        } else {
            obase = (size_t)row * N;
        }
#pragma unroll
        for (int j = 0; j < 4; ++j) {
            const int col0 = n0 + wn + j * 16 + (fq << 2);
            f32x4 v = acc[i][j];
            if (bias) v += *(const f32x4*)(bias + col0);
            if (EMB)  v += *(const f32x4*)(posr + col0);
            if (ACT == 1) {
#pragma unroll
                for (int k = 0; k < 4; ++k) v[k] = geluf(v[k]);
            }
            if (RES) v += *(const f32x4*)(res + obase + col0);
            if (OUTBF) {
                s16x4 o;
#pragma unroll
                for (int k = 0; k < 4; ++k) o[k] = f2bf(v[k]);
                *(s16x4*)((short*)Cout + obase + col0) = o;
            } else {
                *(f32x4*)((float*)Cout + obase + col0) = v;
            }
        }
    }
}

// ---------------- MFMA attention: one wave per (b, head) -----------------------
// qkv is bf16 [B*57][1536] (q|k|v, head-major 64). o is bf16 [B*57][512].
__global__ __launch_bounds__(64) void attn_mfma(const short* __restrict__ qkv,
                                                short* __restrict__ o) {
    __shared__ short Pl[64 * 72];
    __shared__ short Vt[64 * 72];
    const int b = blockIdx.x >> 3, hd = blockIdx.x & 7;
    const int lane = threadIdx.x;
    const int n = lane & 15, q = lane >> 4;
    const short* base = qkv + (size_t)b * SEQ * 1536 + hd * 64;

    // stage V transposed: Vt[d][t] = V[t][d]; zero pad rows t>=57
    {
        const short* vb = base + 1024 + lane;
        for (int t = 0; t < SEQ; ++t) Vt[lane * 72 + t] = vb[(size_t)t * 1536];
        for (int t = SEQ; t < 64; ++t) Vt[lane * 72 + t] = 0;
    }

    // Q,K fragments directly from global (A layout: m=lane&15, k=q*8+j)
    const s16x8 zero8 = {};
    s16x8 qf[4][2], kf[4][2];
#pragma unroll
    for (int ti = 0; ti < 4; ++ti) {
        const int tq = ti * 16 + n;
#pragma unroll
        for (int kk = 0; kk < 2; ++kk) {
            const int ko = kk * 32 + q * 8;
            qf[ti][kk] = (tq < SEQ) ? *(const s16x8*)(base + (size_t)tq * 1536 + ko)       : zero8;
            kf[ti][kk] = (tq < SEQ) ? *(const s16x8*)(base + 512 + (size_t)tq * 1536 + ko) : zero8;
        }
    }

    f32x4 sacc[4][4] = {};
#pragma unroll
    for (int ti = 0; ti < 4; ++ti)
#pragma unroll
        for (int tj = 0; tj < 4; ++tj)
#pragma unroll
            for (int kk = 0; kk < 2; ++kk)
                sacc[ti][tj] = __builtin_amdgcn_mfma_f32_16x16x32_bf16(
                    qf[ti][kk], kf[tj][kk], sacc[ti][tj], 0, 0, 0);

    // softmax per row (row = ti*16 + q*4 + r, cols across tj & 16 lanes)
#pragma unroll
    for (int ti = 0; ti < 4; ++ti) {
#pragma unroll
        for (int r = 0; r < 4; ++r) {
            float v[4]; float mx = -1e30f;
#pragma unroll
            for (int tj = 0; tj < 4; ++tj) {
                float s = sacc[ti][tj][r] * 0.125f;       // SCALE = 64^-0.5
                if (tj * 16 + n >= SEQ) s = -1e30f;       // mask pad cols
                v[tj] = s; mx = fmaxf(mx, s);
            }
            mx = fmaxf(mx, __shfl_xor(mx, 1));
            mx = fmaxf(mx, __shfl_xor(mx, 2));
            mx = fmaxf(mx, __shfl_xor(mx, 4));
            mx = fmaxf(mx, __shfl_xor(mx, 8));
            float sum = 0.f;
#pragma unroll
            for (int tj = 0; tj < 4; ++tj) { v[tj] = __expf(v[tj] - mx); sum += v[tj]; }
            sum += __shfl_xor(sum, 1); sum += __shfl_xor(sum, 2);
            sum += __shfl_xor(sum, 4); sum += __shfl_xor(sum, 8);
            const float inv = 1.f / sum;
            const int row = ti * 16 + q * 4 + r;
#pragma unroll
            for (int tj = 0; tj < 4; ++tj)
                Pl[row * 72 + tj * 16 + n] = f2bf(v[tj] * inv);
        }
    }
    __syncthreads();

    // O = P @ V with swapped operands: lane holds t=ti*16+n fixed,
    // d = td*16 + 4q + r consecutive -> short4 stores.
    f32x4 oacc[4][4] = {};
#pragma unroll
    for (int kk = 0; kk < 2; ++kk) {
        s16x8 pf[4], vf[4];
#pragma unroll
        for (int s = 0; s < 4; ++s) {
            pf[s] = *(const s16x8*)(Pl + (s * 16 + n) * 72 + kk * 32 + q * 8);
            vf[s] = *(const s16x8*)(Vt + (s * 16 + n) * 72 + kk * 32 + q * 8);
        }
#pragma unroll
        for (int ti = 0; ti < 4; ++ti)
#pragma unroll
            for (int td = 0; td < 4; ++td)
                oacc[ti][td] = __builtin_amdgcn_mfma_f32_16x16x32_bf16(
                    vf[td], pf[ti], oacc[ti][td], 0, 0, 0);
    }
#pragma unroll
    for (int ti = 0; ti < 4; ++ti) {
        const int t = ti * 16 + n;
        if (t < SEQ) {
            short* orow = o + ((size_t)(b * SEQ + t)) * DIM + hd * 64 + (q << 2);
#pragma unroll
            for (int td = 0; td < 4; ++td) {
                s16x4 o4;
#pragma unroll
                for (int r = 0; r < 4; ++r) o4[r] = f2bf(oacc[ti][td][r]);
                *(s16x4*)(orow + td * 16) = o4;
            }
        }
    }
}

// ---------------- head: mean-pool + LN + [512x16] matvec -----------------------
__global__ __launch_bounds__(256) void head_kernel(const float* __restrict__ h,
                                                   const float* __restrict__ g,
                                                   const float* __restrict__ bb,
                                                   const float* __restrict__ Wh,
                                                   const float* __restrict__ bh,
                                                   float* __restrict__ out) {
    __shared__ float p[DIM];
    __shared__ float r1[4], r2[4];
    const int b = blockIdx.x;
    const float* hb = h + (size_t)b * SEQ * DIM;
    for (int c = threadIdx.x; c < DIM; c += 256) {
        float s = 0.f;
        for (int t = 0; t < SEQ; ++t) s += hb[t * DIM + c];
        p[c] = s * (1.f / 57.f);
    }
    __syncthreads();
    float s = 0.f;
    for (int c = threadIdx.x; c < DIM; c += 256) s += p[c];
#pragma unroll
    for (int off = 1; off < 64; off <<= 1) s += __shfl_xor(s, off);
    if ((threadIdx.x & 63) == 0) r1[threadIdx.x >> 6] = s;
    __syncthreads();
    const float mu = (r1[0] + r1[1] + r1[2] + r1[3]) * (1.f / 512.f);
    float sq = 0.f;
    for (int c = threadIdx.x; c < DIM; c += 256) { float d = p[c] - mu; sq += d * d; }
#pragma unroll
    for (int off = 1; off < 64; off <<= 1) sq += __shfl_xor(sq, off);
    if ((threadIdx.x & 63) == 0) r2[threadIdx.x >> 6] = sq;
    __syncthreads();
    const float rs = rsqrtf((r2[0] + r2[1] + r2[2] + r2[3]) * (1.f / 512.f) + 1e-5f);
    for (int c = threadIdx.x; c < DIM; c += 256) p[c] = (p[c] - mu) * rs * g[c] + bb[c];
    __syncthreads();
    if (threadIdx.x < 16) {
        float acc = bh[threadIdx.x];
        for (int c = 0; c < DIM; ++c) acc += p[c] * Wh[c * 16 + threadIdx.x];
        out[b * 16 + threadIdx.x] = acc;
    }
}

// ---------------- orchestration -------------------------------------------------
extern "C" void kernel_launch(void* const* d_in, const int* in_sizes, int n_in,
                              void* d_out, int out_size, void* d_ws, size_t ws_size,
                              hipStream_t stream) {
    (void)in_sizes; (void)n_in; (void)out_size; (void)ws_size;
    const float* x    = (const float*)d_in[0];
    const float* We   = (const float*)d_in[1];
    const float* be   = (const float*)d_in[2];
    const float* cls  = (const float*)d_in[3];
    const float* Wqkv = (const float*)d_in[4];
    const float* Wo   = (const float*)d_in[5];
    const float* bo   = (const float*)d_in[6];
    const float* ln1g = (const float*)d_in[7];
    const float* ln1b = (const float*)d_in[8];
    const float* W1   = (const float*)d_in[9];
    const float* b1   = (const float*)d_in[10];
    const float* W2   = (const float*)d_in[11];
    const float* b2   = (const float*)d_in[12];
    const float* ln2g = (const float*)d_in[13];
    const float* ln2b = (const float*)d_in[14];
    const float* lnhg = (const float*)d_in[15];
    const float* lnhb = (const float*)d_in[16];
    const float* Wh   = (const float*)d_in[17];
    const float* bh   = (const float*)d_in[18];

    char* ws = (char*)d_ws;
    float* h    = (float*)(ws);                      // 512*57*512*4  = 59,768,832
    short* bigs = (short*)(ws + 59768832);           // bf16 qkv / MLP hidden (<=179MB slot)
    short* ybf  = (short*)(ws + 239075328);          // 512*57*512*2  = 29,884,416
    short* wbuf = (short*)(ws + 268959744);          // 38,010,880
    short* tokb = (short*)(ws + 306970624);          // 512*56*256*2  = 14,680,064
    float* pos  = (float*)(ws + 321650688);          // 57*512*4      = 116,736

    short* WeT   = wbuf;                             // [512][256]
    short* WqkvT = wbuf + 131072;                    // 6 x [1536][512]
    short* WoT   = WqkvT + 6 * 786432;               // 6 x [512][512]
    short* W1T   = WoT   + 6 * 262144;               // 6 x [2048][512]
    short* W2T   = W1T   + 6 * 1048576;              // 6 x [512][2048]

    pos_kernel<<<114, 256, 0, stream>>>(pos);
    transcvt<<<dim3(16,  8, 1), 256, 0, stream>>>(We,   WeT,    256,  512);
    transcvt<<<dim3(48, 16, 6), 256, 0, stream>>>(Wqkv, WqkvT,  512, 1536);
    transcvt<<<dim3(16, 16, 6), 256, 0, stream>>>(Wo,   WoT,    512,  512);
    transcvt<<<dim3(64, 16, 6), 256, 0, stream>>>(W1,   W1T,    512, 2048);
    transcvt<<<dim3(16, 64, 6), 256, 0, stream>>>(W2,   W2T,   2048,  512);
    spiral_kernel<<<2048, 256, 0, stream>>>(x, tokb);

    // patch embedding fused into h: h[b,1+t,:] = tok@We + be + pos[1+t]
    gemm_bf16<0, false, false, true><<<dim3(4, 224), 256, 0, stream>>>(
        tokb, WeT, be, pos, h, NB * NP, DIM, CHN);
    cls_pos_kernel<<<1024, 256, 0, stream>>>(cls, pos, h);

    const int M = NB * SEQ;   // 29184 = 228*128
    for (int l = 0; l < 6; ++l) {
        ln_kernel<<<M / 4, 256, 0, stream>>>(h, ln1g + l * 512, ln1b + l * 512, ybf);
        gemm_bf16<0, false, true, false><<<dim3(12, 228), 256, 0, stream>>>(
            ybf, WqkvT + (size_t)l * 786432, nullptr, nullptr, bigs, M, 1536, 512);
        attn_mfma<<<NB * 8, 64, 0, stream>>>(bigs, ybf);
        gemm_bf16<0, true, false, false><<<dim3(4, 228), 256, 0, stream>>>(
            ybf, WoT + (size_t)l * 262144, bo + l * 512, h, h, M, 512, 512);
        ln_kernel<<<M / 4, 256, 0, stream>>>(h, ln2g + l * 512, ln2b + l * 512, ybf);
        gemm_bf16<1, false, true, false><<<dim3(16, 228), 256, 0, stream>>>(
            ybf, W1T + (size_t)l * 1048576, b1 + l * 2048, nullptr, bigs, M, 2048, 512);
        gemm_bf16<0, true, false, false><<<dim3(4, 228), 256, 0, stream>>>(
            bigs, W2T + (size_t)l * 1048576, b2 + l * 512, h, h, M, 512, 2048);
    }
    head_kernel<<<NB, 256, 0, stream>>>(h, lnhg, lnhb, Wh, bh, (float*)d_out);
}